// Round 7
// baseline (199.508 us; speedup 1.0000x reference)
//
#include <hip/hip_runtime.h>

#define N_NODES 100000
#define N_EDGES 1600000
#define D 64
#define NB 391            // row buckets of 256 rows
#define PBLK 512          // partition blocks
#define CHUNK ((N_EDGES + PBLK - 1) / PBLK)   // 3125 edges per partition block
#define FLATN (NB * PBLK) // 200192 count-matrix entries
#define SB1 ((FLATN + 255) / 256)             // 782 scan blocks (<1024)
#define NWAVES 3125       // 100000 rows / 32 rows per wave
#define GBLK 782          // gather blocks (4 waves each) -> 3128 waves, all co-resident

__device__ __forceinline__ unsigned short f2b(float f) {
    unsigned u = __float_as_uint(f);
    u += 0x7FFF + ((u >> 16) & 1);            // round-to-nearest-even
    return (unsigned short)(u >> 16);
}
__device__ __forceinline__ float b2f(unsigned short v) {
    return __uint_as_float(((unsigned)v) << 16);
}

// ---- pass 1: per-(block,bucket) edge counts via LDS histogram ----
__global__ void count_kernel(const int* __restrict__ ei, int* __restrict__ counts) {
    __shared__ int h[NB];
    for (int i = threadIdx.x; i < NB; i += 256) h[i] = 0;
    __syncthreads();
    int s = blockIdx.x * CHUNK;
    int e = min(s + CHUNK, N_EDGES);
    for (int i = s + (int)threadIdx.x; i < e; i += 256) {
        int r = ei[i], c = ei[N_EDGES + i];
        if (r != c) atomicAdd(&h[r >> 8], 1);
    }
    __syncthreads();
    for (int i = threadIdx.x; i < NB; i += 256) counts[i * PBLK + blockIdx.x] = h[i];
}

// ---- pass 2a: per-block exclusive scan (in place) ----
__global__ void scan1_kernel(int* __restrict__ a, int* __restrict__ blocksums) {
    __shared__ int s[256];
    int i = blockIdx.x * 256 + threadIdx.x;
    int v = (i < FLATN) ? a[i] : 0;
    s[threadIdx.x] = v;
    __syncthreads();
    for (int off = 1; off < 256; off <<= 1) {
        int t = (threadIdx.x >= off) ? s[threadIdx.x - off] : 0;
        __syncthreads();
        s[threadIdx.x] += t;
        __syncthreads();
    }
    if (i < FLATN) a[i] = s[threadIdx.x] - v;
    if (threadIdx.x == 255) blocksums[blockIdx.x] = s[255];
}

// ---- pass 2b: scan block sums (SB1=782 <= 1024); total -> totalout[0] ----
__global__ void scan2_kernel(int* __restrict__ blocksums, int* __restrict__ totalout) {
    __shared__ int s[1024];
    int t = threadIdx.x;
    int v = (t < SB1) ? blocksums[t] : 0;
    s[t] = v;
    __syncthreads();
    for (int off = 1; off < 1024; off <<= 1) {
        int u = (t >= off) ? s[t - off] : 0;
        __syncthreads();
        s[t] += u;
        __syncthreads();
    }
    if (t < SB1) blocksums[t] = s[t] - v;
    if (t == SB1 - 1) totalout[0] = s[t];  // total non-self edges
}

// ---- pass 3: partition scatter into per-(block,bucket) contiguous runs ----
__global__ void scatter_part_kernel(const int* __restrict__ ei, const int* __restrict__ offsets,
                                    const int* __restrict__ blocksums, int* __restrict__ epack) {
    __shared__ int cur[NB];
    for (int i = threadIdx.x; i < NB; i += 256) {
        int f = i * PBLK + blockIdx.x;
        cur[i] = offsets[f] + blocksums[f >> 8];
    }
    __syncthreads();
    int s = blockIdx.x * CHUNK;
    int e = min(s + CHUNK, N_EDGES);
    for (int i = s + (int)threadIdx.x; i < e; i += 256) {
        int r = ei[i], c = ei[N_EDGES + i];
        if (r != c) {
            int p = atomicAdd(&cur[r >> 8], 1);
            epack[p] = ((r & 255) << 17) | c;   // c < 2^17
        }
    }
}

// ---- pass 4: per-bucket bin sort by (wave-of-32, col-slice); emit waveseg, dinv, sorted2 ----
__global__ void binsort_kernel(const int* __restrict__ offsets, const int* __restrict__ blocksums,
                               const int* __restrict__ totalsrc,
                               const int* __restrict__ epack, int* __restrict__ waveseg,
                               float* __restrict__ dinv, int* __restrict__ sorted2) {
    __shared__ int h[256];
    __shared__ int bh[64];
    __shared__ int sc[64];
    __shared__ int cur[64];
    int b = blockIdx.x;
    int t = threadIdx.x;
    int f0 = b * PBLK;
    int base = offsets[f0] + blocksums[f0 >> 8];
    int end;
    if (b + 1 < NB) {
        int f1 = (b + 1) * PBLK;
        end = offsets[f1] + blocksums[f1 >> 8];
    } else {
        end = totalsrc[0];
    }
    h[t] = 0;
    if (t < 64) bh[t] = 0;
    __syncthreads();
    for (int i = base + t; i < end; i += 256) {
        int p = epack[i];
        int rlow = p >> 17;
        atomicAdd(&h[rlow], 1);
        atomicAdd(&bh[((rlow >> 5) << 3) | ((p & 0x1FFFF) >> 14)], 1);
    }
    __syncthreads();
    if (t < 64) sc[t] = bh[t];
    __syncthreads();
    for (int off = 1; off < 64; off <<= 1) {
        int u = 0;
        if (t < 64 && t >= off) u = sc[t - off];
        __syncthreads();
        if (t < 64) sc[t] += u;
        __syncthreads();
    }
    if (t < 64) {
        int excl = sc[t] - bh[t];
        waveseg[b * 64 + t] = base + excl;
        cur[t] = base + excl;
    }
    int row = b * 256 + t;
    if (row < N_NODES) dinv[row] = rsqrtf((float)(1 + h[t]));
    __syncthreads();
    for (int i = base + t; i < end; i += 256) {
        int p = epack[i];
        int rlow = p >> 17;
        int bin = ((rlow >> 5) << 3) | ((p & 0x1FFFF) >> 14);
        int pos = atomicAdd(&cur[bin], 1);
        sorted2[pos] = p;
    }
}

// ---- pass 5: xs[i][d] = bf16(x[i][d] * dinv[i]) ----
__global__ void convert_kernel(const float* __restrict__ x, const float* __restrict__ dinv,
                               unsigned short* __restrict__ xs) {
    int i = blockIdx.x * blockDim.x + threadIdx.x;   // over N*D/4
    if (i >= N_NODES * D / 4) return;
    float4 v = ((const float4*)x)[i];
    float di = dinv[(i * 4) >> 6];
    ushort4 o;
    o.x = f2b(v.x * di);
    o.y = f2b(v.y * di);
    o.z = f2b(v.z * di);
    o.w = f2b(v.w * di);
    ((ushort4*)xs)[i] = o;
}

// ---- pass 6: gather. One wave per 32 rows, slice-ordered edges, LDS acc. ----
__global__ __launch_bounds__(256, 4)
void gather2_kernel(const unsigned short* __restrict__ xs, const float* __restrict__ dinv,
                    const int* __restrict__ waveseg, const int* __restrict__ sorted2,
                    float* __restrict__ out) {
    __shared__ float accs[4 * 32 * 64];       // 32 KB: per-wave private 32x64 f32
    int wl = threadIdx.x >> 6;
    int d = threadIdx.x & 63;
    int w = blockIdx.x * 4 + wl;
    if (w >= NWAVES) return;
    float* a = &accs[wl * 2048];
#pragma unroll
    for (int i = 0; i < 32; i++) a[i * 64 + d] = 0.f;
    int b = w >> 3, wib = w & 7;
    int segb = 0;
    if (d <= 8) segb = waveseg[b * 64 + wib * 8 + d];
    float dv = (d < 32) ? dinv[w * 32 + d] : 0.f;
    for (int s = 0; s < 8; s++) {            // slice 7 is empty (c>>14 <= 6); loop skips it
        int start = __shfl(segb, s);
        int end = __shfl(segb, s + 1);
        for (int j = start; j < end; j += 64) {
            int ent = 0;
            if (j + d < end) ent = __builtin_nontemporal_load(&sorted2[j + d]);
            int n = min(64, end - j);
            int k = 0;
            for (; k + 4 <= n; k += 4) {
                int e0 = __shfl(ent, k);
                int e1 = __shfl(ent, k + 1);
                int e2 = __shfl(ent, k + 2);
                int e3 = __shfl(ent, k + 3);
                float v0 = b2f(xs[(e0 & 0x1FFFF) * D + d]);  // 4 independent L2-hit loads
                float v1 = b2f(xs[(e1 & 0x1FFFF) * D + d]);
                float v2 = b2f(xs[(e2 & 0x1FFFF) * D + d]);
                float v3 = b2f(xs[(e3 & 0x1FFFF) * D + d]);
                a[((e0 >> 17) & 31) * 64 + d] += v0;
                a[((e1 >> 17) & 31) * 64 + d] += v1;
                a[((e2 >> 17) & 31) * 64 + d] += v2;
                a[((e3 >> 17) & 31) * 64 + d] += v3;
            }
            for (; k < n; k++) {
                int e = __shfl(ent, k);
                a[((e >> 17) & 31) * 64 + d] += b2f(xs[(e & 0x1FFFF) * D + d]);
            }
        }
    }
    int row0 = w * 32;
#pragma unroll
    for (int i = 0; i < 32; i++) {
        int row = row0 + i;
        float self = b2f(xs[row * D + d]);   // self-loop (xs already carries dinv[row])
        float val = __shfl(dv, i) * (a[i * 64 + d] + self);
        __builtin_nontemporal_store(val, &out[row * D + d]);
    }
}

extern "C" void kernel_launch(void* const* d_in, const int* in_sizes, int n_in,
                              void* d_out, int out_size, void* d_ws, size_t ws_size,
                              hipStream_t stream) {
    const float* x = (const float*)d_in[0];
    const int* ei = (const int*)d_in[1];
    float* out = (float*)d_out;

    // workspace layout (~27 MB)
    int* offsets = (int*)d_ws;                        // [FLATN]
    int* blocksums = offsets + FLATN;                 // [1024]
    int* waveseg = blocksums + 1024;                  // [NB*64 + 1] (+1 holds edge total)
    int* totalp = waveseg + NB * 64;                  // alias: totalp[0] = total edges
    float* dinv = (float*)(waveseg + NB * 64 + 1);    // [N_NODES]
    int* epack = (int*)(dinv + N_NODES);              // [N_EDGES]
    int* sorted2 = epack + N_EDGES;                   // [N_EDGES]
    unsigned short* xs = (unsigned short*)(sorted2 + N_EDGES); // [N_NODES*D]

    count_kernel<<<PBLK, 256, 0, stream>>>(ei, offsets);
    scan1_kernel<<<SB1, 256, 0, stream>>>(offsets, blocksums);
    scan2_kernel<<<1, 1024, 0, stream>>>(blocksums, totalp);
    scatter_part_kernel<<<PBLK, 256, 0, stream>>>(ei, offsets, blocksums, epack);
    binsort_kernel<<<NB, 256, 0, stream>>>(offsets, blocksums, totalp, epack, waveseg, dinv, sorted2);
    convert_kernel<<<(N_NODES * D / 4 + 255) / 256, 256, 0, stream>>>(x, dinv, xs);
    gather2_kernel<<<GBLK, 256, 0, stream>>>(xs, dinv, waveseg, sorted2, out);
}